// Round 6
// baseline (8982.581 us; speedup 1.0000x reference)
//
#include <hip/hip_runtime.h>

#define T_STEPS 512
#define BB 64
#define EE 300
#define EP 320
#define HH 512
#define HB (BB*HH)        // halves per h slot (65536 B)
#define RING 8
#define XPSLOT 524288     // bytes per xp slot: 64 rows * 512 cols * 16B (f32 r,z,n,pad)

typedef _Float16 f16x8 __attribute__((ext_vector_type(8)));
typedef float f32x4 __attribute__((ext_vector_type(4)));
typedef int i32x4 __attribute__((ext_vector_type(4)));

__device__ __forceinline__ f32x4 mf(f16x8 a, f16x8 b, f32x4 c) {
  return __builtin_amdgcn_mfma_f32_16x16x32_f16(a, b, c, 0, 0, 0);
}

struct HMat { i32x4 q[16]; };   // 64 VGPRs: one lane's 16 A-fragments of a 16-row tile

// 16 back-to-back MALL (sc1) 16B loads + FULL drain in ONE asm block
#define LOADS16_MALL                                                 \
    "global_load_dwordx4 %0,  %16, %17 sc1\n\t"                      \
    "global_load_dwordx4 %1,  %16, %17 offset:64 sc1\n\t"            \
    "global_load_dwordx4 %2,  %16, %17 offset:128 sc1\n\t"           \
    "global_load_dwordx4 %3,  %16, %17 offset:192 sc1\n\t"           \
    "global_load_dwordx4 %4,  %16, %17 offset:256 sc1\n\t"           \
    "global_load_dwordx4 %5,  %16, %17 offset:320 sc1\n\t"           \
    "global_load_dwordx4 %6,  %16, %17 offset:384 sc1\n\t"           \
    "global_load_dwordx4 %7,  %16, %17 offset:448 sc1\n\t"           \
    "global_load_dwordx4 %8,  %16, %17 offset:512 sc1\n\t"           \
    "global_load_dwordx4 %9,  %16, %17 offset:576 sc1\n\t"           \
    "global_load_dwordx4 %10, %16, %17 offset:640 sc1\n\t"           \
    "global_load_dwordx4 %11, %16, %17 offset:704 sc1\n\t"           \
    "global_load_dwordx4 %12, %16, %17 offset:768 sc1\n\t"           \
    "global_load_dwordx4 %13, %16, %17 offset:832 sc1\n\t"           \
    "global_load_dwordx4 %14, %16, %17 offset:896 sc1\n\t"           \
    "global_load_dwordx4 %15, %16, %17 offset:960 sc1\n\t"           \
    "s_waitcnt vmcnt(0)"

#define HM_OUTS(m) "=v"((m).q[0]), "=v"((m).q[1]), "=v"((m).q[2]), "=v"((m).q[3]),   \
                   "=v"((m).q[4]), "=v"((m).q[5]), "=v"((m).q[6]), "=v"((m).q[7]),   \
                   "=v"((m).q[8]), "=v"((m).q[9]), "=v"((m).q[10]), "=v"((m).q[11]), \
                   "=v"((m).q[12]), "=v"((m).q[13]), "=v"((m).q[14]), "=v"((m).q[15])

__device__ __forceinline__ void load16_mall(HMat& m, const void* base, int voff) {
  asm volatile(LOADS16_MALL : HM_OUTS(m) : "v"(voff), "s"(base) : "memory");
}

// fused: 16 h-loads + 4 xp (f32x4) loads, ONE drain. xp rows at 8192B stride → 4 voffs.
#define LOADS16_XP4                                                  \
    "global_load_dwordx4 %0,  %20, %21 sc1\n\t"                      \
    "global_load_dwordx4 %1,  %20, %21 offset:64 sc1\n\t"            \
    "global_load_dwordx4 %2,  %20, %21 offset:128 sc1\n\t"           \
    "global_load_dwordx4 %3,  %20, %21 offset:192 sc1\n\t"           \
    "global_load_dwordx4 %4,  %20, %21 offset:256 sc1\n\t"           \
    "global_load_dwordx4 %5,  %20, %21 offset:320 sc1\n\t"           \
    "global_load_dwordx4 %6,  %20, %21 offset:384 sc1\n\t"           \
    "global_load_dwordx4 %7,  %20, %21 offset:448 sc1\n\t"           \
    "global_load_dwordx4 %8,  %20, %21 offset:512 sc1\n\t"           \
    "global_load_dwordx4 %9,  %20, %21 offset:576 sc1\n\t"           \
    "global_load_dwordx4 %10, %20, %21 offset:640 sc1\n\t"           \
    "global_load_dwordx4 %11, %20, %21 offset:704 sc1\n\t"           \
    "global_load_dwordx4 %12, %20, %21 offset:768 sc1\n\t"           \
    "global_load_dwordx4 %13, %20, %21 offset:832 sc1\n\t"           \
    "global_load_dwordx4 %14, %20, %21 offset:896 sc1\n\t"           \
    "global_load_dwordx4 %15, %20, %21 offset:960 sc1\n\t"           \
    "global_load_dwordx4 %16, %22, %26 sc1\n\t"                      \
    "global_load_dwordx4 %17, %23, %26 sc1\n\t"                      \
    "global_load_dwordx4 %18, %24, %26 sc1\n\t"                      \
    "global_load_dwordx4 %19, %25, %26 sc1\n\t"                      \
    "s_waitcnt vmcnt(0)"

__device__ __forceinline__ void load_h_xp(HMat& m, f32x4* xp,
                                          const void* hbase, int hvoff,
                                          const void* xbase, const int* vx) {
  asm volatile(LOADS16_XP4
    : HM_OUTS(m), "=v"(xp[0]), "=v"(xp[1]), "=v"(xp[2]), "=v"(xp[3])
    : "v"(hvoff), "s"(hbase), "v"(vx[0]), "v"(vx[1]), "v"(vx[2]), "v"(vx[3]), "s"(xbase)
    : "memory");
}

__device__ __forceinline__ void load_xp4(f32x4* xp, const void* xbase, const int* vx) {
  asm volatile(
    "global_load_dwordx4 %0, %4, %8 sc1\n\t"
    "global_load_dwordx4 %1, %5, %8 sc1\n\t"
    "global_load_dwordx4 %2, %6, %8 sc1\n\t"
    "global_load_dwordx4 %3, %7, %8 sc1\n\t"
    "s_waitcnt vmcnt(0)"
    : "=v"(xp[0]), "=v"(xp[1]), "=v"(xp[2]), "=v"(xp[3])
    : "v"(vx[0]), "v"(vx[1]), "v"(vx[2]), "v"(vx[3]), "s"(xbase) : "memory");
}

// batched x-prefetch: 10 plain cached loads + full drain (x0 is immutable)
__device__ __forceinline__ void loadx10_wait(i32x4* xq, const void* base, int voff) {
  asm volatile(
    "global_load_dwordx4 %0, %10, %11\n\t"
    "global_load_dwordx4 %1, %10, %11 offset:64\n\t"
    "global_load_dwordx4 %2, %10, %11 offset:128\n\t"
    "global_load_dwordx4 %3, %10, %11 offset:192\n\t"
    "global_load_dwordx4 %4, %10, %11 offset:256\n\t"
    "global_load_dwordx4 %5, %10, %11 offset:320\n\t"
    "global_load_dwordx4 %6, %10, %11 offset:384\n\t"
    "global_load_dwordx4 %7, %10, %11 offset:448\n\t"
    "global_load_dwordx4 %8, %10, %11 offset:512\n\t"
    "global_load_dwordx4 %9, %10, %11 offset:576\n\t"
    "s_waitcnt vmcnt(0)"
    : "=v"(xq[0]), "=v"(xq[1]), "=v"(xq[2]), "=v"(xq[3]), "=v"(xq[4]),
      "=v"(xq[5]), "=v"(xq[6]), "=v"(xq[7]), "=v"(xq[8]), "=v"(xq[9])
    : "v"(voff), "s"(base) : "memory");
}

__device__ __forceinline__ f16x8 fragq(i32x4 q) {
  union { i32x4 i; f16x8 v; } x; x.i = q; return x.v;
}

// publish to MALL (proven pair with sc1 loads)
__device__ __forceinline__ void st16_mall(void* p, f16x8 v) {
  i32x4 iv;
  __builtin_memcpy(&iv, &v, 16);
  asm volatile("global_store_dwordx4 %0, %1, off sc0 sc1" :: "v"(p), "v"(iv) : "memory");
}
__device__ __forceinline__ void st16f(void* p, f32x4 v) {
  i32x4 iv;
  __builtin_memcpy(&iv, &v, 16);
  asm volatile("global_store_dwordx4 %0, %1, off sc0 sc1" :: "v"(p), "v"(iv) : "memory");
}

// per-WAVE joint poll over SINGLE-WORD counters (producers atomicAdd(+1) per step;
// condition "all 32 producers >= step s" == "counter >= 32*s"). A poll iteration
// touches 3 cache lines TOTAL (all lanes broadcast-load the same 3 addresses) vs
// ~64 scattered lines for per-producer flag sweeps — ~20x less MALL poll traffic,
// with ZERO write sharing (each counter has its own 64B line; adds are atomic).
// Targets <= 0 pass trivially (counters monotone from 0).
__device__ __forceinline__ void wave_wait3(const int* c1, int t1,
                                           const int* c2, int t2,
                                           const int* c3, int t3) {
  for (;;) {
    int v1, v2, v3;
    asm volatile(
      "global_load_dword %0, %3, off sc1\n\t"
      "global_load_dword %1, %4, off sc1\n\t"
      "global_load_dword %2, %5, off sc1\n\t"
      "s_waitcnt vmcnt(0)"
      : "=v"(v1), "=v"(v2), "=v"(v3) : "v"(c1), "v"(c2), "v"(c3) : "memory");
    if (v1 >= t1 && v2 >= t2 && v3 >= t3) return;
    __builtin_amdgcn_s_sleep(1);
  }
}

__device__ __forceinline__ float sigf(float x) { return 1.f / (1.f + __expf(-x)); }

struct B3 { f16x8 r, z, n; };
// LDS weight read: [chunk][gate(3)][jj(16)][40 halves] — 40-half jj stride spreads the
// 16 cols across bank windows 4*((5*jj+quad) mod 8): uniform, max 2-way (free).
__device__ __forceinline__ B3 ldsB(const _Float16* wl, int chunk, int jj, int kq) {
  B3 o;
  const _Float16* p = wl + chunk * 1920 + jj * 40 + kq;
  o.r = *(const f16x8*)p;
  o.z = *(const f16x8*)(p + 640);
  o.n = *(const f16x8*)(p + 1280);
  return o;
}

__global__ void prep_x0(const int* __restrict__ texts, const float* __restrict__ emb,
                        _Float16* __restrict__ x0) {
  const size_t N = (size_t)T_STEPS * BB * EP;
  const size_t stride = (size_t)gridDim.x * blockDim.x;
  for (size_t i = (size_t)blockIdx.x * blockDim.x + threadIdx.x; i < N; i += stride) {
    int e = (int)(i % EP);
    size_t tb = i / EP;
    float v = 0.f;
    if (e < EE) v = emb[(size_t)texts[tb] * EE + e];
    x0[i] = (_Float16)v;
  }
}

__global__ void prep_b(const float* __restrict__ bih0, const float* __restrict__ bhh0,
                       const float* __restrict__ bih1, const float* __restrict__ bhh1,
                       float* __restrict__ bias0, float* __restrict__ bias1) {
  int i = blockIdx.x * blockDim.x + threadIdx.x;
  if (i < HH) {
    bias0[i]        = bih0[i] + bhh0[i];
    bias0[512 + i]  = bih0[512 + i] + bhh0[512 + i];
    bias0[1024 + i] = bih0[1024 + i];
    bias0[1536 + i] = bhh0[1024 + i];
    bias1[i]        = bih1[i] + bhh1[i];
    bias1[512 + i]  = bih1[512 + i] + bhh1[512 + i];
    bias1[1024 + i] = bih1[1024 + i];
    bias1[1536 + i] = bhh1[1024 + i];
  }
}

// 128 WGs x 256 threads, 4 roles x 32 WGs; each WG = 4 independent waves, one per
// 16-row batch group (GRU rows are independent -> 8 decoupled pipelines).
//   role 0 (L0): h1 recurrence, Whh0 in LDS, consumes precomputed xp0 (f32).
//   role 1 (P0): x0 @ Wih0^T -> xp0 ring (16 slots), runs ~15 steps ahead (off path).
//   role 2 (P1): h1 @ Wih1^T -> xp1 ring (4 slots), pipelined between L0 and L1.
//   role 3 (L1): h2 recurrence, Whh1 in LDS, consumes xp1; pooled atomics in tail.
// Recurrent loops have NO serial tail: wait -> one fused drain -> 48 MFMA -> act ->
// publish -> counter-add. No __syncthreads in any step loop.
__global__ __launch_bounds__(256, 1) void gru_persistent(
    const _Float16* __restrict__ x0,
    const float* __restrict__ Wih0, const float* __restrict__ Whh0,
    const float* __restrict__ Wih1, const float* __restrict__ Whh1,
    const float* __restrict__ bias0, const float* __restrict__ bias1,
    _Float16* h1ring, _Float16* h2buf, float* xp0ring, float* xp1ring,
    float* pooled, int* cnt0, int* cntP0, int* cntP1, int* cnt1)
{
  const int wg   = blockIdx.x;
  const int role = wg >> 5;          // 0=L0 1=P0 2=P1 3=L1
  const int w    = wg & 31;          // column slice 0..31
  const int jb   = w * 16;           // 16 h-cols per WG
  const int tid  = threadIdx.x;
  const int g    = tid >> 6;         // wave = batch group, rows g*16..+15
  const int lane = tid & 63;
  const int quad = lane >> 4;
  const int l15  = lane & 15;
  const int kq   = quad * 8;
  const int hoff = (g * 16 + l15) * 1024 + quad * 16;  // byte voffset into an h slot

  __shared__ alignas(16) _Float16 wlds[30720];     // 16 chunks x 1920 halves = 60 KiB
  __shared__ alignas(16) _Float16 tile[4][16][16]; // per-wave publish transpose, 2 KiB

  // ---- one-time LDS weight fill (fp32 global -> f16, 40-half jj stride) ----
  {
    const float* Wsrc = (role == 0) ? Whh0 : (role == 1) ? Wih0
                      : (role == 2) ? Wih1 : Whh1;
    const int nch  = (role == 1) ? 10 : 16;
    const int Ksrc = (role == 1) ? EE : HH;
    for (int idx = tid; idx < nch * 192; idx += 256) {
      int q = idx & 3, jj = (idx >> 2) & 15, g3 = (idx >> 6) % 3, ch = idx / 192;
      int row = g3 * 512 + jb + jj;
      _Float16* dst = wlds + ch * 1920 + g3 * 640 + jj * 40 + q * 8;
      int colb = ch * 32 + q * 8;
      #pragma unroll
      for (int e = 0; e < 8; ++e) {
        int col = colb + e;
        dst[e] = (col < Ksrc) ? (_Float16)Wsrc[(size_t)row * Ksrc + col] : (_Float16)0.f;
      }
    }
  }
  __syncthreads();

  // loop-invariant xp voffsets: [row 64][hcol 512][gate pad4] f32 -> row stride 8192 B
  int vx[4];
  #pragma unroll
  for (int rg = 0; rg < 4; ++rg)
    vx[rg] = (g * 16 + quad * 4 + rg) * 8192 + (jb + l15) * 16;

  // one counter per (role, group): own 64B line (g*16 ints)
  int* c0  = cnt0  + g * 16;
  int* cP0 = cntP0 + g * 16;
  int* cP1 = cntP1 + g * 16;
  int* c1  = cnt1  + g * 16;

  if (role == 0) {            // ---------------- L0: h1 recurrence ----------------
    const int j = jb + l15;
    const float br = bias0[j], bz = bias0[512 + j];
    const float bnx = bias0[1024 + j], bnh = bias0[1536 + j];
    float hprev[4] = {0.f, 0.f, 0.f, 0.f};
    _Float16 (*tc)[16] = tile[g];
    for (int s = 0; s < T_STEPS; ++s) {
      // own-group recurrence; P1 ring throttle; xp0[s] ready (P0 runs ahead)
      wave_wait3(c0, 32 * s, cP1, 32 * (s - 7), cP0, 32 * (s + 1));
      f32x4 hR = {0.f,0.f,0.f,0.f}, hZ = {0.f,0.f,0.f,0.f}, hN = {0.f,0.f,0.f,0.f};
      f32x4 xp[4];
      const void* xb = (const char*)xp0ring + (size_t)(s & 15) * XPSLOT;
      if (s >= 1) {
        HMat hA;
        load_h_xp(hA, xp, h1ring + (size_t)((s - 1) & (RING - 1)) * HB, hoff, xb, vx);
        #pragma unroll 4
        for (int c = 0; c < 16; ++c) {
          f16x8 a = fragq(hA.q[c]);
          B3 bb = ldsB(wlds, c, l15, kq);
          hR = mf(a, bb.r, hR); hZ = mf(a, bb.z, hZ); hN = mf(a, bb.n, hN);
        }
      } else {
        load_xp4(xp, xb, vx);
      }
      #pragma unroll
      for (int rg = 0; rg < 4; ++rg) {
        float r = sigf(xp[rg][0] + hR[rg] + br);
        float z = sigf(xp[rg][1] + hZ[rg] + bz);
        float n = tanhf(xp[rg][2] + bnx + r * (hN[rg] + bnh));
        float hnew = (1.f - z) * n + z * hprev[rg];
        hprev[rg] = hnew;
        tc[quad * 4 + rg][l15] = (_Float16)hnew;
      }
      if (lane < 32) {                      // 16 rows x 32B per wave
        int row = lane & 15, hb = lane >> 4;
        f16x8 v = *(const f16x8*)&tc[row][hb * 8];
        st16_mall(h1ring + (size_t)(s & (RING - 1)) * HB
                  + (size_t)(g * 16 + row) * HH + jb + hb * 8, v);
      }
      __builtin_amdgcn_s_waitcnt(0);
      if (lane == 0) atomicAdd(c0, 1);
    }
  } else if (role == 1) {     // ---------------- P0: x projection (ahead) ----------------
    const int xoff = (g * 16 + l15) * 640 + quad * 16;
    for (int t = 0; t < T_STEPS; ++t) {
      wave_wait3(c0, 32 * (t - 15), c0, 32 * (t - 15), c0, 32 * (t - 15));
      i32x4 xq[10];
      loadx10_wait(xq, x0 + (size_t)t * BB * EP, xoff);
      f32x4 aR = {0.f,0.f,0.f,0.f}, aZ = {0.f,0.f,0.f,0.f}, aN = {0.f,0.f,0.f,0.f};
      #pragma unroll 5
      for (int c = 0; c < 10; ++c) {
        f16x8 a = fragq(xq[c]);
        B3 bb = ldsB(wlds, c, l15, kq);
        aR = mf(a, bb.r, aR); aZ = mf(a, bb.z, aZ); aN = mf(a, bb.n, aN);
      }
      char* xb = (char*)xp0ring + (size_t)(t & 15) * XPSLOT;
      #pragma unroll
      for (int rg = 0; rg < 4; ++rg) {
        f32x4 v = {aR[rg], aZ[rg], aN[rg], 0.f};
        st16f(xb + vx[rg], v);
      }
      __builtin_amdgcn_s_waitcnt(0);
      if (lane == 0) atomicAdd(cP0, 1);
    }
  } else if (role == 2) {     // ---------------- P1: h1 -> xp1 projection ----------------
    for (int t = 0; t < T_STEPS; ++t) {
      // h1[t] ready; xp1 ring throttle vs L1
      wave_wait3(c0, 32 * (t + 1), c1, 32 * (t - 3), c0, 32 * (t + 1));
      HMat A;
      load16_mall(A, h1ring + (size_t)(t & (RING - 1)) * HB, hoff);
      f32x4 aR = {0.f,0.f,0.f,0.f}, aZ = {0.f,0.f,0.f,0.f}, aN = {0.f,0.f,0.f,0.f};
      #pragma unroll 4
      for (int c = 0; c < 16; ++c) {
        f16x8 a = fragq(A.q[c]);
        B3 bb = ldsB(wlds, c, l15, kq);
        aR = mf(a, bb.r, aR); aZ = mf(a, bb.z, aZ); aN = mf(a, bb.n, aN);
      }
      char* xb = (char*)xp1ring + (size_t)(t & 3) * XPSLOT;
      #pragma unroll
      for (int rg = 0; rg < 4; ++rg) {
        f32x4 v = {aR[rg], aZ[rg], aN[rg], 0.f};
        st16f(xb + vx[rg], v);
      }
      __builtin_amdgcn_s_waitcnt(0);
      if (lane == 0) atomicAdd(cP1, 1);
    }
  } else {                    // ---------------- L1: h2 recurrence ----------------
    const int j = jb + l15;
    const float br = bias1[j], bz = bias1[512 + j];
    const float bnx = bias1[1024 + j], bnh = bias1[1536 + j];
    float hprev[4] = {0.f, 0.f, 0.f, 0.f};
    _Float16 (*tc)[16] = tile[g];
    for (int t = 0; t < T_STEPS; ++t) {
      // own recurrence; xp1[t] ready
      wave_wait3(c1, 32 * t, cP1, 32 * (t + 1), c1, 32 * t);
      f32x4 hR = {0.f,0.f,0.f,0.f}, hZ = {0.f,0.f,0.f,0.f}, hN = {0.f,0.f,0.f,0.f};
      f32x4 xp[4];
      const void* xb = (const char*)xp1ring + (size_t)(t & 3) * XPSLOT;
      if (t >= 1) {
        HMat hA;
        load_h_xp(hA, xp, h2buf + (size_t)((t - 1) & 1) * HB, hoff, xb, vx);
        #pragma unroll 4
        for (int c = 0; c < 16; ++c) {
          f16x8 a = fragq(hA.q[c]);
          B3 bb = ldsB(wlds, c, l15, kq);
          hR = mf(a, bb.r, hR); hZ = mf(a, bb.z, hZ); hN = mf(a, bb.n, hN);
        }
      } else {
        load_xp4(xp, xb, vx);
      }
      #pragma unroll
      for (int rg = 0; rg < 4; ++rg) {
        float r = sigf(xp[rg][0] + hR[rg] + br);
        float z = sigf(xp[rg][1] + hZ[rg] + bz);
        float n = tanhf(xp[rg][2] + bnx + r * (hN[rg] + bnh));
        float hnew = (1.f - z) * n + z * hprev[rg];
        hprev[rg] = hnew;
        tc[quad * 4 + rg][l15] = (_Float16)hnew;
      }
      if (lane < 32) {
        int row = lane & 15, hb = lane >> 4;
        f16x8 v = *(const f16x8*)&tc[row][hb * 8];
        st16_mall(h2buf + (size_t)(t & 1) * HB
                  + (size_t)(g * 16 + row) * HH + jb + hb * 8, v);
      }
      __builtin_amdgcn_s_waitcnt(0);
      if (lane == 0) atomicAdd(c1, 1);
      // tail (off the counter path): pooled partial sums, raw; /64 in FC
      if (lane < 16) {
        float sum = 0.f;
        #pragma unroll
        for (int r = 0; r < 16; ++r) sum += (float)tc[r][lane];
        atomicAdd(pooled + (size_t)t * HH + jb + lane, sum);
      }
    }
  }
}

__global__ void fc_kernel(const float* __restrict__ pooled, const float* __restrict__ fcW,
                          const float* __restrict__ fcb, float* __restrict__ out) {
  const int t = blockIdx.x;
  const int lane = threadIdx.x;  // 64 = one wave
  float a0 = 0.f, a1 = 0.f, a2 = 0.f, a3 = 0.f, a4 = 0.f;
  for (int jj = lane; jj < HH; jj += 64) {
    float p = pooled[(size_t)t * HH + jj];
    a0 += p * fcW[jj];
    a1 += p * fcW[512 + jj];
    a2 += p * fcW[1024 + jj];
    a3 += p * fcW[1536 + jj];
    a4 += p * fcW[2048 + jj];
  }
  #pragma unroll
  for (int off = 32; off > 0; off >>= 1) {
    a0 += __shfl_down(a0, off, 64);
    a1 += __shfl_down(a1, off, 64);
    a2 += __shfl_down(a2, off, 64);
    a3 += __shfl_down(a3, off, 64);
    a4 += __shfl_down(a4, off, 64);
  }
  if (lane == 0) {
    const float sc = 1.f / 64.f;
    out[t * 5 + 0] = a0 * sc + fcb[0];
    out[t * 5 + 1] = a1 * sc + fcb[1];
    out[t * 5 + 2] = a2 * sc + fcb[2];
    out[t * 5 + 3] = a3 * sc + fcb[3];
    out[t * 5 + 4] = a4 * sc + fcb[4];
  }
}

extern "C" void kernel_launch(void* const* d_in, const int* in_sizes, int n_in,
                              void* d_out, int out_size, void* d_ws, size_t ws_size,
                              hipStream_t stream) {
  const int*   texts = (const int*)  d_in[0];
  const float* emb   = (const float*)d_in[1];
  const float* Wih0  = (const float*)d_in[2];
  const float* Whh0  = (const float*)d_in[3];
  const float* bih0  = (const float*)d_in[4];
  const float* bhh0  = (const float*)d_in[5];
  const float* Wih1  = (const float*)d_in[6];
  const float* Whh1  = (const float*)d_in[7];
  const float* bih1  = (const float*)d_in[8];
  const float* bhh1  = (const float*)d_in[9];
  const float* fcW   = (const float*)d_in[10];
  const float* fcb   = (const float*)d_in[11];
  float* out = (float*)d_out;

  char* ws = (char*)d_ws;
  int*      cnt0    = (int*)ws;                      // 4 grp x 64B lines
  int*      cntP0   = (int*)(ws + 4096);
  int*      cntP1   = (int*)(ws + 8192);
  int*      cnt1    = (int*)(ws + 12288);
  float*    pooled  = (float*)(ws + 16384);          // 1048576 B [512][512] f32
  _Float16* h1ring  = (_Float16*)(ws + 1064960);     // 524288 B (8 x 64x512 f16)
  _Float16* h2buf   = (_Float16*)(ws + 1589248);     // 131072 B (2 slots)
  float*    xp1ring = (float*)(ws + 1720320);        // 2097152 B (4 x 512KB)
  float*    xp0ring = (float*)(ws + 3817472);        // 8388608 B (16 x 512KB)
  _Float16* x0      = (_Float16*)(ws + 12206080);    // 20971520 B [512][64][320]
  float*    bias0   = (float*)(ws + 33177600);       // 8192 B (r,z,nx,nh)
  float*    bias1   = (float*)(ws + 33185792);       // 8192 B
  // total ws use: 33193984 B

  hipMemsetAsync(ws, 0, 1064960, stream);  // counters + pooled = zeros
  prep_x0<<<4096, 256, 0, stream>>>(texts, emb, x0);
  prep_b<<<2, 256, 0, stream>>>(bih0, bhh0, bih1, bhh1, bias0, bias1);
  gru_persistent<<<128, 256, 0, stream>>>(x0, Wih0, Whh0, Wih1, Whh1, bias0, bias1,
                                          h1ring, h2buf, xp0ring, xp1ring, pooled,
                                          cnt0, cntP0, cntP1, cnt1);
  fc_kernel<<<512, 64, 0, stream>>>(pooled, fcW, fcb, out);
}

// Round 7
// 4525.749 us; speedup vs baseline: 1.9848x; 1.9848x over previous
//
#include <hip/hip_runtime.h>

#define T_STEPS 512
#define BB 64
#define EE 300
#define EP 320
#define HH 512
#define HB (BB*HH)        // halves per h slot (65536 B)
#define XPSLOT 524288     // bytes per xp slot: 64 rows * 512 cols * 16B (f32 r,z,n,pad)
#define FS 16             // flag stride in ints (64 B): producer-exclusive cache line

typedef _Float16 f16x8 __attribute__((ext_vector_type(8)));
typedef float f32x4 __attribute__((ext_vector_type(4)));
typedef int i32x4 __attribute__((ext_vector_type(4)));

__device__ __forceinline__ f32x4 mf(f16x8 a, f16x8 b, f32x4 c) {
  return __builtin_amdgcn_mfma_f32_16x16x32_f16(a, b, c, 0, 0, 0);
}

struct HMat { i32x4 q[16]; };   // 64 VGPRs: one lane's 16 A-fragments of a 16-row tile

// 16 back-to-back PLAIN (L2-cached) 16B loads + FULL drain in ONE asm block.
// h slots are WRITE-ONCE per dispatch: first reader on an XCD fills L2 from MALL,
// the other consumer WGs on that XCD hit L2 (~8x less MALL read traffic).
#define LOADS16_PLAIN                                                \
    "global_load_dwordx4 %0,  %16, %17\n\t"                          \
    "global_load_dwordx4 %1,  %16, %17 offset:64\n\t"                \
    "global_load_dwordx4 %2,  %16, %17 offset:128\n\t"               \
    "global_load_dwordx4 %3,  %16, %17 offset:192\n\t"               \
    "global_load_dwordx4 %4,  %16, %17 offset:256\n\t"               \
    "global_load_dwordx4 %5,  %16, %17 offset:320\n\t"               \
    "global_load_dwordx4 %6,  %16, %17 offset:384\n\t"               \
    "global_load_dwordx4 %7,  %16, %17 offset:448\n\t"               \
    "global_load_dwordx4 %8,  %16, %17 offset:512\n\t"               \
    "global_load_dwordx4 %9,  %16, %17 offset:576\n\t"               \
    "global_load_dwordx4 %10, %16, %17 offset:640\n\t"               \
    "global_load_dwordx4 %11, %16, %17 offset:704\n\t"               \
    "global_load_dwordx4 %12, %16, %17 offset:768\n\t"               \
    "global_load_dwordx4 %13, %16, %17 offset:832\n\t"               \
    "global_load_dwordx4 %14, %16, %17 offset:896\n\t"               \
    "global_load_dwordx4 %15, %16, %17 offset:960\n\t"               \
    "s_waitcnt vmcnt(0)"

#define HM_OUTS(m) "=v"((m).q[0]), "=v"((m).q[1]), "=v"((m).q[2]), "=v"((m).q[3]),   \
                   "=v"((m).q[4]), "=v"((m).q[5]), "=v"((m).q[6]), "=v"((m).q[7]),   \
                   "=v"((m).q[8]), "=v"((m).q[9]), "=v"((m).q[10]), "=v"((m).q[11]), \
                   "=v"((m).q[12]), "=v"((m).q[13]), "=v"((m).q[14]), "=v"((m).q[15])

__device__ __forceinline__ void load16_plain(HMat& m, const void* base, int voff) {
  asm volatile(LOADS16_PLAIN : HM_OUTS(m) : "v"(voff), "s"(base) : "memory");
}

// fused: 16 PLAIN h-loads (write-once buffer) + 4 sc1 xp loads (reused ring — MUST
// bypass L2 or a stale line from 16 steps ago could be served), ONE drain.
#define LOADS16_XP4_MIX                                              \
    "global_load_dwordx4 %0,  %20, %21\n\t"                          \
    "global_load_dwordx4 %1,  %20, %21 offset:64\n\t"                \
    "global_load_dwordx4 %2,  %20, %21 offset:128\n\t"               \
    "global_load_dwordx4 %3,  %20, %21 offset:192\n\t"               \
    "global_load_dwordx4 %4,  %20, %21 offset:256\n\t"               \
    "global_load_dwordx4 %5,  %20, %21 offset:320\n\t"               \
    "global_load_dwordx4 %6,  %20, %21 offset:384\n\t"               \
    "global_load_dwordx4 %7,  %20, %21 offset:448\n\t"               \
    "global_load_dwordx4 %8,  %20, %21 offset:512\n\t"               \
    "global_load_dwordx4 %9,  %20, %21 offset:576\n\t"               \
    "global_load_dwordx4 %10, %20, %21 offset:640\n\t"               \
    "global_load_dwordx4 %11, %20, %21 offset:704\n\t"               \
    "global_load_dwordx4 %12, %20, %21 offset:768\n\t"               \
    "global_load_dwordx4 %13, %20, %21 offset:832\n\t"               \
    "global_load_dwordx4 %14, %20, %21 offset:896\n\t"               \
    "global_load_dwordx4 %15, %20, %21 offset:960\n\t"               \
    "global_load_dwordx4 %16, %22, %26 sc1\n\t"                      \
    "global_load_dwordx4 %17, %23, %26 sc1\n\t"                      \
    "global_load_dwordx4 %18, %24, %26 sc1\n\t"                      \
    "global_load_dwordx4 %19, %25, %26 sc1\n\t"                      \
    "s_waitcnt vmcnt(0)"

__device__ __forceinline__ void load_h_xp(HMat& m, f32x4* xp,
                                          const void* hbase, int hvoff,
                                          const void* xbase, const int* vx) {
  asm volatile(LOADS16_XP4_MIX
    : HM_OUTS(m), "=v"(xp[0]), "=v"(xp[1]), "=v"(xp[2]), "=v"(xp[3])
    : "v"(hvoff), "s"(hbase), "v"(vx[0]), "v"(vx[1]), "v"(vx[2]), "v"(vx[3]), "s"(xbase)
    : "memory");
}

__device__ __forceinline__ void load_xp4(f32x4* xp, const void* xbase, const int* vx) {
  asm volatile(
    "global_load_dwordx4 %0, %4, %8 sc1\n\t"
    "global_load_dwordx4 %1, %5, %8 sc1\n\t"
    "global_load_dwordx4 %2, %6, %8 sc1\n\t"
    "global_load_dwordx4 %3, %7, %8 sc1\n\t"
    "s_waitcnt vmcnt(0)"
    : "=v"(xp[0]), "=v"(xp[1]), "=v"(xp[2]), "=v"(xp[3])
    : "v"(vx[0]), "v"(vx[1]), "v"(vx[2]), "v"(vx[3]), "s"(xbase) : "memory");
}

// batched x-prefetch: 10 plain cached loads + full drain (x0 is immutable)
__device__ __forceinline__ void loadx10_wait(i32x4* xq, const void* base, int voff) {
  asm volatile(
    "global_load_dwordx4 %0, %10, %11\n\t"
    "global_load_dwordx4 %1, %10, %11 offset:64\n\t"
    "global_load_dwordx4 %2, %10, %11 offset:128\n\t"
    "global_load_dwordx4 %3, %10, %11 offset:192\n\t"
    "global_load_dwordx4 %4, %10, %11 offset:256\n\t"
    "global_load_dwordx4 %5, %10, %11 offset:320\n\t"
    "global_load_dwordx4 %6, %10, %11 offset:384\n\t"
    "global_load_dwordx4 %7, %10, %11 offset:448\n\t"
    "global_load_dwordx4 %8, %10, %11 offset:512\n\t"
    "global_load_dwordx4 %9, %10, %11 offset:576\n\t"
    "s_waitcnt vmcnt(0)"
    : "=v"(xq[0]), "=v"(xq[1]), "=v"(xq[2]), "=v"(xq[3]), "=v"(xq[4]),
      "=v"(xq[5]), "=v"(xq[6]), "=v"(xq[7]), "=v"(xq[8]), "=v"(xq[9])
    : "v"(voff), "s"(base) : "memory");
}

__device__ __forceinline__ f16x8 fragq(i32x4 q) {
  union { i32x4 i; f16x8 v; } x; x.i = q; return x.v;
}

// publish: write-through to MALL (no L2 allocate) so consumers' L2 fills are fresh
__device__ __forceinline__ void st16_mall(void* p, f16x8 v) {
  i32x4 iv;
  __builtin_memcpy(&iv, &v, 16);
  asm volatile("global_store_dwordx4 %0, %1, off sc0 sc1" :: "v"(p), "v"(iv) : "memory");
}
__device__ __forceinline__ void st16f(void* p, f32x4 v) {
  i32x4 iv;
  __builtin_memcpy(&iv, &v, 16);
  asm volatile("global_store_dwordx4 %0, %1, off sc0 sc1" :: "v"(p), "v"(iv) : "memory");
}
__device__ __forceinline__ void st4_dev(int* p, int v) {
  asm volatile("global_store_dword %0, %1, off sc0 sc1" :: "v"(p), "v"(v) : "memory");
}

// per-WAVE joint poll, R1's proven layout: producer-exclusive 64B flag lines.
// lanes 0-31 poll pa[lane*FS]>=ta, lanes 32-63 poll pb[(lane-32)*FS]>=tb; ALL lanes
// also poll pc[(lane&31)*FS]>=tc_. Targets <=0 pass trivially (flags monotone >=0).
__device__ __forceinline__ void wave_wait(const int* pa, int ta,
                                          const int* pb, int tb,
                                          const int* pc, int tc_) {
  const int lane = threadIdx.x & 63;
  const int* p1 = (lane < 32) ? (pa + lane * FS) : (pb + (lane - 32) * FS);
  const int t1 = (lane < 32) ? ta : tb;
  const int* p2 = pc + (lane & 31) * FS;
  for (;;) {
    int v1, v2;
    asm volatile(
      "global_load_dword %0, %2, off sc1\n\t"
      "global_load_dword %1, %3, off sc1\n\t"
      "s_waitcnt vmcnt(0)"
      : "=v"(v1), "=v"(v2) : "v"(p1), "v"(p2) : "memory");
    if (__all((v1 >= t1) && (v2 >= tc_))) return;
    __builtin_amdgcn_s_sleep(2);
  }
}

__device__ __forceinline__ float sigf(float x) { return 1.f / (1.f + __expf(-x)); }

struct B3 { f16x8 r, z, n; };
// LDS weight read: [chunk][gate(3)][jj(16)][40 halves] — 40-half jj stride spreads the
// 16 cols across bank windows 4*((5*jj+quad) mod 8): uniform, max 2-way (free).
__device__ __forceinline__ B3 ldsB(const _Float16* wl, int chunk, int jj, int kq) {
  B3 o;
  const _Float16* p = wl + chunk * 1920 + jj * 40 + kq;
  o.r = *(const f16x8*)p;
  o.z = *(const f16x8*)(p + 640);
  o.n = *(const f16x8*)(p + 1280);
  return o;
}

__global__ void prep_x0(const int* __restrict__ texts, const float* __restrict__ emb,
                        _Float16* __restrict__ x0) {
  const size_t N = (size_t)T_STEPS * BB * EP;
  const size_t stride = (size_t)gridDim.x * blockDim.x;
  for (size_t i = (size_t)blockIdx.x * blockDim.x + threadIdx.x; i < N; i += stride) {
    int e = (int)(i % EP);
    size_t tb = i / EP;
    float v = 0.f;
    if (e < EE) v = emb[(size_t)texts[tb] * EE + e];
    x0[i] = (_Float16)v;
  }
}

__global__ void prep_b(const float* __restrict__ bih0, const float* __restrict__ bhh0,
                       const float* __restrict__ bih1, const float* __restrict__ bhh1,
                       float* __restrict__ bias0, float* __restrict__ bias1) {
  int i = blockIdx.x * blockDim.x + threadIdx.x;
  if (i < HH) {
    bias0[i]        = bih0[i] + bhh0[i];
    bias0[512 + i]  = bih0[512 + i] + bhh0[512 + i];
    bias0[1024 + i] = bih0[1024 + i];
    bias0[1536 + i] = bhh0[1024 + i];
    bias1[i]        = bih1[i] + bhh1[i];
    bias1[512 + i]  = bih1[512 + i] + bhh1[512 + i];
    bias1[1024 + i] = bih1[1024 + i];
    bias1[1536 + i] = bhh1[1024 + i];
  }
}

// 128 WGs x 256 threads, 4 roles x 32 WGs; each WG = 4 independent waves, one per
// 16-row batch group (GRU rows are independent -> 8 decoupled pipelines).
//   role 0 (L0): h1 recurrence, Whh0 in LDS, consumes precomputed xp0 (f32).
//   role 1 (P0): x0 @ Wih0^T -> xp0 ring (16 slots), runs ~15 steps ahead (off path).
//   role 2 (P1): h1 @ Wih1^T -> xp1 ring (4 slots), pipelined between L0 and L1.
//   role 3 (L1): h2 recurrence, Whh1 in LDS, consumes xp1; pooled atomics in tail.
// h1/h2 are WRITE-ONCE sequences (512 x 64KB): consumers use plain cached loads
// (L2 read amplification); no h-ring throttles needed. xp rings stay sc1.
__global__ __launch_bounds__(256, 1) void gru_persistent(
    const _Float16* __restrict__ x0,
    const float* __restrict__ Wih0, const float* __restrict__ Whh0,
    const float* __restrict__ Wih1, const float* __restrict__ Whh1,
    const float* __restrict__ bias0, const float* __restrict__ bias1,
    _Float16* h1seq, _Float16* h2seq, float* xp0ring, float* xp1ring,
    float* pooled, int* flags0, int* flagsP0, int* flagsP1, int* flags1)
{
  const int wg   = blockIdx.x;
  const int role = wg >> 5;          // 0=L0 1=P0 2=P1 3=L1
  const int w    = wg & 31;          // column slice 0..31
  const int jb   = w * 16;           // 16 h-cols per WG
  const int tid  = threadIdx.x;
  const int g    = tid >> 6;         // wave = batch group, rows g*16..+15
  const int lane = tid & 63;
  const int quad = lane >> 4;
  const int l15  = lane & 15;
  const int kq   = quad * 8;
  const int hoff = (g * 16 + l15) * 1024 + quad * 16;  // byte voffset into an h slot

  __shared__ alignas(16) _Float16 wlds[30720];     // 16 chunks x 1920 halves = 60 KiB
  __shared__ alignas(16) _Float16 tile[4][16][16]; // per-wave publish transpose, 2 KiB

  // ---- one-time LDS weight fill (fp32 global -> f16, 40-half jj stride) ----
  {
    const float* Wsrc = (role == 0) ? Whh0 : (role == 1) ? Wih0
                      : (role == 2) ? Wih1 : Whh1;
    const int nch  = (role == 1) ? 10 : 16;
    const int Ksrc = (role == 1) ? EE : HH;
    for (int idx = tid; idx < nch * 192; idx += 256) {
      int q = idx & 3, jj = (idx >> 2) & 15, g3 = (idx >> 6) % 3, ch = idx / 192;
      int row = g3 * 512 + jb + jj;
      _Float16* dst = wlds + ch * 1920 + g3 * 640 + jj * 40 + q * 8;
      int colb = ch * 32 + q * 8;
      #pragma unroll
      for (int e = 0; e < 8; ++e) {
        int col = colb + e;
        dst[e] = (col < Ksrc) ? (_Float16)Wsrc[(size_t)row * Ksrc + col] : (_Float16)0.f;
      }
    }
  }
  __syncthreads();

  // loop-invariant xp voffsets: [row 64][hcol 512][gate pad4] f32 -> row stride 8192 B
  int vx[4];
  #pragma unroll
  for (int rg = 0; rg < 4; ++rg)
    vx[rg] = (g * 16 + quad * 4 + rg) * 8192 + (jb + l15) * 16;

  const int* fg0  = flags0  + g * 32 * FS;   // 32 producers x 64B per group
  const int* fgP0 = flagsP0 + g * 32 * FS;
  const int* fgP1 = flagsP1 + g * 32 * FS;
  const int* fg1  = flags1  + g * 32 * FS;

  if (role == 0) {            // ---------------- L0: h1 recurrence ----------------
    const int j = jb + l15;
    const float br = bias0[j], bz = bias0[512 + j];
    const float bnx = bias0[1024 + j], bnh = bias0[1536 + j];
    int* myf = flags0 + (g * 32 + w) * FS;
    float hprev[4] = {0.f, 0.f, 0.f, 0.f};
    _Float16 (*tc)[16] = tile[g];
    for (int s = 0; s < T_STEPS; ++s) {
      // own-group recurrence; xp0[s] ready (P0 runs ahead). No h-ring throttle.
      wave_wait(fg0, s, fg0, s, fgP0, s + 1);
      f32x4 hR = {0.f,0.f,0.f,0.f}, hZ = {0.f,0.f,0.f,0.f}, hN = {0.f,0.f,0.f,0.f};
      f32x4 xp[4];
      const void* xb = (const char*)xp0ring + (size_t)(s & 15) * XPSLOT;
      if (s >= 1) {
        HMat hA;
        load_h_xp(hA, xp, h1seq + (size_t)(s - 1) * HB, hoff, xb, vx);
        #pragma unroll 4
        for (int c = 0; c < 16; ++c) {
          f16x8 a = fragq(hA.q[c]);
          B3 bb = ldsB(wlds, c, l15, kq);
          hR = mf(a, bb.r, hR); hZ = mf(a, bb.z, hZ); hN = mf(a, bb.n, hN);
        }
      } else {
        load_xp4(xp, xb, vx);
      }
      #pragma unroll
      for (int rg = 0; rg < 4; ++rg) {
        float r = sigf(xp[rg][0] + hR[rg] + br);
        float z = sigf(xp[rg][1] + hZ[rg] + bz);
        float n = tanhf(xp[rg][2] + bnx + r * (hN[rg] + bnh));
        float hnew = (1.f - z) * n + z * hprev[rg];
        hprev[rg] = hnew;
        tc[quad * 4 + rg][l15] = (_Float16)hnew;
      }
      if (lane < 32) {                      // 16 rows x 32B per wave
        int row = lane & 15, hb = lane >> 4;
        f16x8 v = *(const f16x8*)&tc[row][hb * 8];
        st16_mall(h1seq + (size_t)s * HB
                  + (size_t)(g * 16 + row) * HH + jb + hb * 8, v);
      }
      __builtin_amdgcn_s_waitcnt(0);
      if (lane == 0) st4_dev(myf, s + 1);
    }
  } else if (role == 1) {     // ---------------- P0: x projection (ahead) ----------------
    int* myf = flagsP0 + (g * 32 + w) * FS;
    const int xoff = (g * 16 + l15) * 640 + quad * 16;
    for (int t = 0; t < T_STEPS; ++t) {
      wave_wait(fg0, t - 15, fg0, t - 15, fg0, t - 15);   // xp0 ring throttle only
      i32x4 xq[10];
      loadx10_wait(xq, x0 + (size_t)t * BB * EP, xoff);
      f32x4 aR = {0.f,0.f,0.f,0.f}, aZ = {0.f,0.f,0.f,0.f}, aN = {0.f,0.f,0.f,0.f};
      #pragma unroll 5
      for (int c = 0; c < 10; ++c) {
        f16x8 a = fragq(xq[c]);
        B3 bb = ldsB(wlds, c, l15, kq);
        aR = mf(a, bb.r, aR); aZ = mf(a, bb.z, aZ); aN = mf(a, bb.n, aN);
      }
      char* xb = (char*)xp0ring + (size_t)(t & 15) * XPSLOT;
      #pragma unroll
      for (int rg = 0; rg < 4; ++rg) {
        f32x4 v = {aR[rg], aZ[rg], aN[rg], 0.f};
        st16f(xb + vx[rg], v);
      }
      __builtin_amdgcn_s_waitcnt(0);
      if (lane == 0) st4_dev(myf, t + 1);
    }
  } else if (role == 2) {     // ---------------- P1: h1 -> xp1 projection ----------------
    int* myf = flagsP1 + (g * 32 + w) * FS;
    for (int t = 0; t < T_STEPS; ++t) {
      wave_wait(fg0, t + 1, fg1, t - 3, fg0, t + 1);  // h1[t] ready; xp1 ring throttle
      HMat A;
      load16_plain(A, h1seq + (size_t)t * HB, hoff);
      f32x4 aR = {0.f,0.f,0.f,0.f}, aZ = {0.f,0.f,0.f,0.f}, aN = {0.f,0.f,0.f,0.f};
      #pragma unroll 4
      for (int c = 0; c < 16; ++c) {
        f16x8 a = fragq(A.q[c]);
        B3 bb = ldsB(wlds, c, l15, kq);
        aR = mf(a, bb.r, aR); aZ = mf(a, bb.z, aZ); aN = mf(a, bb.n, aN);
      }
      char* xb = (char*)xp1ring + (size_t)(t & 3) * XPSLOT;
      #pragma unroll
      for (int rg = 0; rg < 4; ++rg) {
        f32x4 v = {aR[rg], aZ[rg], aN[rg], 0.f};
        st16f(xb + vx[rg], v);
      }
      __builtin_amdgcn_s_waitcnt(0);
      if (lane == 0) st4_dev(myf, t + 1);
    }
  } else {                    // ---------------- L1: h2 recurrence ----------------
    const int j = jb + l15;
    const float br = bias1[j], bz = bias1[512 + j];
    const float bnx = bias1[1024 + j], bnh = bias1[1536 + j];
    int* myf = flags1 + (g * 32 + w) * FS;
    float hprev[4] = {0.f, 0.f, 0.f, 0.f};
    _Float16 (*tc)[16] = tile[g];
    for (int t = 0; t < T_STEPS; ++t) {
      wave_wait(fg1, t, fgP1, t + 1, fg1, t);  // own recurrence; xp1[t] ready
      f32x4 hR = {0.f,0.f,0.f,0.f}, hZ = {0.f,0.f,0.f,0.f}, hN = {0.f,0.f,0.f,0.f};
      f32x4 xp[4];
      const void* xb = (const char*)xp1ring + (size_t)(t & 3) * XPSLOT;
      if (t >= 1) {
        HMat hA;
        load_h_xp(hA, xp, h2seq + (size_t)(t - 1) * HB, hoff, xb, vx);
        #pragma unroll 4
        for (int c = 0; c < 16; ++c) {
          f16x8 a = fragq(hA.q[c]);
          B3 bb = ldsB(wlds, c, l15, kq);
          hR = mf(a, bb.r, hR); hZ = mf(a, bb.z, hZ); hN = mf(a, bb.n, hN);
        }
      } else {
        load_xp4(xp, xb, vx);
      }
      #pragma unroll
      for (int rg = 0; rg < 4; ++rg) {
        float r = sigf(xp[rg][0] + hR[rg] + br);
        float z = sigf(xp[rg][1] + hZ[rg] + bz);
        float n = tanhf(xp[rg][2] + bnx + r * (hN[rg] + bnh));
        float hnew = (1.f - z) * n + z * hprev[rg];
        hprev[rg] = hnew;
        tc[quad * 4 + rg][l15] = (_Float16)hnew;
      }
      if (lane < 32) {
        int row = lane & 15, hb = lane >> 4;
        f16x8 v = *(const f16x8*)&tc[row][hb * 8];
        st16_mall(h2seq + (size_t)t * HB
                  + (size_t)(g * 16 + row) * HH + jb + hb * 8, v);
      }
      __builtin_amdgcn_s_waitcnt(0);
      if (lane == 0) st4_dev(myf, t + 1);
      // tail (off the flag path): pooled partial sums, raw; /64 in FC
      if (lane < 16) {
        float sum = 0.f;
        #pragma unroll
        for (int r = 0; r < 16; ++r) sum += (float)tc[r][lane];
        atomicAdd(pooled + (size_t)t * HH + jb + lane, sum);
      }
    }
  }
}

__global__ void fc_kernel(const float* __restrict__ pooled, const float* __restrict__ fcW,
                          const float* __restrict__ fcb, float* __restrict__ out) {
  const int t = blockIdx.x;
  const int lane = threadIdx.x;  // 64 = one wave
  float a0 = 0.f, a1 = 0.f, a2 = 0.f, a3 = 0.f, a4 = 0.f;
  for (int jj = lane; jj < HH; jj += 64) {
    float p = pooled[(size_t)t * HH + jj];
    a0 += p * fcW[jj];
    a1 += p * fcW[512 + jj];
    a2 += p * fcW[1024 + jj];
    a3 += p * fcW[1536 + jj];
    a4 += p * fcW[2048 + jj];
  }
  #pragma unroll
  for (int off = 32; off > 0; off >>= 1) {
    a0 += __shfl_down(a0, off, 64);
    a1 += __shfl_down(a1, off, 64);
    a2 += __shfl_down(a2, off, 64);
    a3 += __shfl_down(a3, off, 64);
    a4 += __shfl_down(a4, off, 64);
  }
  if (lane == 0) {
    const float sc = 1.f / 64.f;
    out[t * 5 + 0] = a0 * sc + fcb[0];
    out[t * 5 + 1] = a1 * sc + fcb[1];
    out[t * 5 + 2] = a2 * sc + fcb[2];
    out[t * 5 + 3] = a3 * sc + fcb[3];
    out[t * 5 + 4] = a4 * sc + fcb[4];
  }
}

extern "C" void kernel_launch(void* const* d_in, const int* in_sizes, int n_in,
                              void* d_out, int out_size, void* d_ws, size_t ws_size,
                              hipStream_t stream) {
  const int*   texts = (const int*)  d_in[0];
  const float* emb   = (const float*)d_in[1];
  const float* Wih0  = (const float*)d_in[2];
  const float* Whh0  = (const float*)d_in[3];
  const float* bih0  = (const float*)d_in[4];
  const float* bhh0  = (const float*)d_in[5];
  const float* Wih1  = (const float*)d_in[6];
  const float* Whh1  = (const float*)d_in[7];
  const float* bih1  = (const float*)d_in[8];
  const float* bhh1  = (const float*)d_in[9];
  const float* fcW   = (const float*)d_in[10];
  const float* fcb   = (const float*)d_in[11];
  float* out = (float*)d_out;

  char* ws = (char*)d_ws;
  int*      flags0  = (int*)ws;                      // 8192 B (4 grp x 32 x 64B)
  int*      flagsP0 = (int*)(ws + 8192);             // 8192 B
  int*      flagsP1 = (int*)(ws + 16384);            // 8192 B
  int*      flags1  = (int*)(ws + 24576);            // 8192 B
  float*    pooled  = (float*)(ws + 32768);          // 1048576 B [512][512] f32
  _Float16* h1seq   = (_Float16*)(ws + 1081344);     // 33554432 B (512 x 64KB, write-once)
  _Float16* h2seq   = (_Float16*)(ws + 34635776);    // 33554432 B (512 x 64KB, write-once)
  float*    xp1ring = (float*)(ws + 68190208);       // 2097152 B (4 x 512KB)
  float*    xp0ring = (float*)(ws + 70287360);       // 8388608 B (16 x 512KB)
  _Float16* x0      = (_Float16*)(ws + 78675968);    // 20971520 B [512][64][320]
  float*    bias0   = (float*)(ws + 99647488);       // 8192 B (r,z,nx,nh)
  float*    bias1   = (float*)(ws + 99655680);       // 8192 B
  // total ws use: 99663872 B (~95 MiB) — fits MALL (256 MiB) with inputs

  hipMemsetAsync(ws, 0, 1081344, stream);  // flags + pooled = zeros
  prep_x0<<<4096, 256, 0, stream>>>(texts, emb, x0);
  prep_b<<<2, 256, 0, stream>>>(bih0, bhh0, bih1, bhh1, bias0, bias1);
  gru_persistent<<<128, 256, 0, stream>>>(x0, Wih0, Whh0, Wih1, Whh1, bias0, bias1,
                                          h1seq, h2seq, xp0ring, xp1ring, pooled,
                                          flags0, flagsP0, flagsP1, flags1);
  fc_kernel<<<512, 64, 0, stream>>>(pooled, fcW, fcb, out);
}